// Round 11
// baseline (216.882 us; speedup 1.0000x reference)
//
#include <hip/hip_runtime.h>
#include <hip/hip_bf16.h>

// Problem constants (B=4, N=4096, F=64)
#define NB 4
#define NN 4096
#define NF 64
#define TSTEP 4            // j-tile steps per block (2080 = 520*4 per batch)
#define BLKS_PER_B 520

typedef __attribute__((ext_vector_type(8))) short bf16x8;   // 8 bf16 (MFMA A/B frag)
typedef __attribute__((ext_vector_type(4))) float f32x4;    // MFMA C/D frag

union S8 { unsigned short u[8]; bf16x8 v; };

__device__ __forceinline__ unsigned short f2bf(float x) {
    unsigned int uu = __builtin_bit_cast(unsigned int, x);
    uu += 0x7fffu + ((uu >> 16) & 1u);
    return (unsigned short)(uu >> 16);
}

// compiler-native bf16 convert: emits v_cvt_pk_bf16_f32 (pairs get fused)
__device__ __forceinline__ short f2bf_s(float x) {
    return __builtin_bit_cast(short, __float2bfloat16(x));
}

// ---------------------------------------------------------------------------
// Fused pre-pass. Q pre-scaled by 1/64 (= 1/sqrt(N); leaky-relu positively
// homogeneous, rest linear). V and W_att use the "C-frag chain" k-map
//   k = c*32 + 16*(e>>2) + 4*(lane>>4) + (e&3)
// so swapped-QK^T C-frags and PV C-frags feed the next MFMA with no
// cross-lane movement. d_out PRE-FILLED with broadcast b_att, so partial
// segments are pure atomic adds (bias counted exactly once).
// ---------------------------------------------------------------------------
__global__ __launch_bounds__(256)
void prep_all(const float* __restrict__ Q, const float* __restrict__ K,
              const float* __restrict__ V, const float* __restrict__ W,
              const float* __restrict__ batt,
              short* __restrict__ QF, short* __restrict__ KF,
              short* __restrict__ VF, short* __restrict__ WF,
              float* __restrict__ out) {
    int tid = blockIdx.x * 256 + threadIdx.x;

    if (tid < 262144) {                       // ---- Q/K frags ----
        int sel = tid >> 17;
        int r   = tid & 0x1FFFF;
        int l  = r & 63;
        int c  = (r >> 6) & 1;
        int rg = (r >> 7) & 255;
        int b  = r >> 15;
        const float* src = sel ? K : Q;
        short*       dst = sel ? KF : QF;
        float sc = sel ? 1.0f : 0.015625f;    // 1/sqrt(4096) folded into Q

        int row = rg * 16 + (l & 15);
        int k0  = c * 32 + (l >> 4) * 8;
        const float4* s4 = (const float4*)src;
        int base4 = (b * NN + row) * 32 + (k0 >> 1);

        S8 ar, ai;
        #pragma unroll
        for (int m = 0; m < 4; ++m) {
            float4 f = s4[base4 + m];
            ar.u[2 * m]     = f2bf(f.x * sc);
            ar.u[2 * m + 1] = f2bf(f.z * sc);
            ai.u[2 * m]     = f2bf(f.y * sc);
            ai.u[2 * m + 1] = f2bf(f.w * sc);
        }
        int cid0 = ((b * 256 + rg) * 2 + c) * 2;
        *(bf16x8*)(dst + (cid0 + 0) * 512 + l * 8) = ar.v;
        *(bf16x8*)(dst + (cid0 + 1) * 512 + l * 8) = ai.v;
    } else if (tid < 393216) {                // ---- V frags (chain k-map) ----
        int r = tid - 262144;
        int l  = r & 63;
        int c  = (r >> 6) & 1;
        int ft = (r >> 7) & 3;
        int jt = (r >> 9) & 63;
        int b  = (r >> 15) & 3;

        int f  = ft * 16 + (l & 15);
        int jb = jt * 64 + c * 32 + (l >> 4) * 4;
        const float2* s2 = (const float2*)V;

        S8 ar, ai;
        #pragma unroll
        for (int e = 0; e < 8; ++e) {
            int j = jb + (e >> 2) * 16 + (e & 3);
            float2 gg = s2[(b * NN + j) * 64 + f];
            ar.u[e] = f2bf(gg.x);
            ai.u[e] = f2bf(gg.y);
        }
        int cid0 = (((b * 64 + jt) * 4 + ft) * 2 + c) * 2;
        *(bf16x8*)(VF + (cid0 + 0) * 512 + l * 8) = ar.v;
        *(bf16x8*)(VF + (cid0 + 1) * 512 + l * 8) = ai.v;
    } else if (tid < 393728) {                // ---- W_att frags (chain k-map) ----
        int r = tid - 393216;
        int l  = r & 63;
        int c  = (r >> 6) & 1;
        int gt = r >> 7;
        int grow = gt * 16 + (l & 15);
        const float* sp = W + grow * 64;
        S8 a;
        #pragma unroll
        for (int e = 0; e < 8; ++e) {
            int f = c * 32 + (e >> 2) * 16 + (l >> 4) * 4 + (e & 3);
            a.u[e] = f2bf(sp[f]);
        }
        *(bf16x8*)(WF + ((gt * 2 + c) * 64 + l) * 8) = a.v;
    } else {                                  // ---- prefill d_out with b_att ----
        int r = tid - 393728;                 // 524288 float4's = 2M floats
        int g0 = (2 * r) & 63;
        float b0 = batt[g0];
        float b1 = batt[g0 + 1];
        float4 zz = {b0, b0, b1, b1};
        ((float4*)out)[r] = zz;
    }
}

// triangular inversion: largest it with it*(it+1)/2 <= g
__device__ __forceinline__ int tri_inv(int g) {
    int it = (int)((__builtin_sqrtf(8.0f * (float)g + 1.0f) - 1.0f) * 0.5f);
    while ((it + 1) * (it + 2) / 2 <= g) ++it;
    while (it * (it + 1) / 2 > g) --it;
    return it;
}

// ---------------------------------------------------------------------------
// One 64x64 (i,j) tile step for one wave (16 q-rows). DIAG is compile-time:
// the causal mask VALU exists only in the peeled diagonal instantiation.
// V-frags for the whole tile are prefetched first (independent of S results)
// so their latency hides under the S-phase MFMA + VALU.
// ---------------------------------------------------------------------------
template<bool DIAG>
__device__ __forceinline__ void do_tile(int b, int it, int jt, int w, int l,
                                        int r16, int lb,
                                        const bf16x8 (&qf)[2][2], f32x4 (&o)[4][2],
                                        const short* __restrict__ KF,
                                        const short* __restrict__ VF) {
    const f32x4 z = {0.f, 0.f, 0.f, 0.f};

    // prefetch all 16 V frags for this j-tile
    bf16x8 vf_[4][4];
    #pragma unroll
    for (int ft = 0; ft < 4; ++ft) {
        int cid0 = (((b * 64 + jt) * 4 + ft) * 2) * 2;
        #pragma unroll
        for (int q = 0; q < 4; ++q)
            vf_[ft][q] = *(const bf16x8*)(VF + (cid0 + q) * 512 + l * 8);
    }

    bf16x8 pa0r, pa0i, pa1r, pa1i;   // PV B-frags, c-chunk 0/1, ch r/i

    #pragma unroll
    for (int ct = 0; ct < 4; ++ct) {
        bf16x8 kf[2][2];
        int rg = jt * 4 + ct;
        #pragma unroll
        for (int c = 0; c < 2; ++c)
            #pragma unroll
            for (int ch = 0; ch < 2; ++ch)
                kf[c][ch] = *(const bf16x8*)(KF + (((b * 256 + rg) * 2 + c) * 2 + ch) * 512 + l * 8);

        // swapped: D[j on reg-axis][i on lane&15]
        f32x4 t1 = __builtin_amdgcn_mfma_f32_16x16x32_bf16(kf[0][0], qf[0][0], z, 0, 0, 0);
        t1 = __builtin_amdgcn_mfma_f32_16x16x32_bf16(kf[1][0], qf[1][0], t1, 0, 0, 0);
        f32x4 t2 = __builtin_amdgcn_mfma_f32_16x16x32_bf16(kf[0][1], qf[0][1], z, 0, 0, 0);
        t2 = __builtin_amdgcn_mfma_f32_16x16x32_bf16(kf[1][1], qf[1][1], t2, 0, 0, 0);
        f32x4 si = __builtin_amdgcn_mfma_f32_16x16x32_bf16(kf[0][1], qf[0][0], z, 0, 0, 0);
        si = __builtin_amdgcn_mfma_f32_16x16x32_bf16(kf[1][1], qf[1][0], si, 0, 0, 0);
        si = __builtin_amdgcn_mfma_f32_16x16x32_bf16(kf[0][0], qf[0][1], si, 0, 0, 0);
        si = __builtin_amdgcn_mfma_f32_16x16x32_bf16(kf[1][0], qf[1][1], si, 0, 0, 0);

        #pragma unroll
        for (int reg = 0; reg < 4; ++reg) {
            float sr = t1[reg] - t2[reg];
            float sv = si[reg];
            float wr = sr * (sr >= 0.f ? 1.0f : 0.01f);   // 2-op leaky
            float wi = sv * (sv >= 0.f ? 1.0f : 0.01f);
            if constexpr (DIAG) {
                int jg = ct * 16 + lb * 4 + reg;   // j offset in 64-tile
                int ig = w * 16 + r16;             // i offset in 64-tile
                if (jg > ig) { wr = 0.f; wi = 0.f; }
            }
            short hr = f2bf_s(wr);
            short hi = f2bf_s(wi);
            int e = (ct & 1) * 4 + reg;            // constant after unroll
            if (ct < 2) { pa0r[e] = hr; pa0i[e] = hi; }
            else        { pa1r[e] = hr; pa1i[e] = hi; }
        }
    }

    // PV: o = mfma(A=V^T frag, B=W frag, o); k-maps match by construction
    #pragma unroll
    for (int ft = 0; ft < 4; ++ft) {
        o[ft][0] = __builtin_amdgcn_mfma_f32_16x16x32_bf16(vf_[ft][0], pa0r, o[ft][0], 0, 0, 0);
        o[ft][0] = __builtin_amdgcn_mfma_f32_16x16x32_bf16(vf_[ft][2], pa1r, o[ft][0], 0, 0, 0);
        o[ft][1] = __builtin_amdgcn_mfma_f32_16x16x32_bf16(vf_[ft][1], pa0i, o[ft][1], 0, 0, 0);
        o[ft][1] = __builtin_amdgcn_mfma_f32_16x16x32_bf16(vf_[ft][3], pa1i, o[ft][1], 0, 0, 0);
    }
}

// ---------------------------------------------------------------------------
// Main kernel. 2080 blocks x 256 threads (4 waves), no LDS; all inter-MFMA
// handoffs in VGPRs. Diagonal tile peeled (template<DIAG>) so the main loop
// has zero mask VALU. Epilogue: i on regs, g on lanes -> coalesced float2
// stores (whole i-tile) or contiguous fp32 atomicAdds (bias via prefill).
// ---------------------------------------------------------------------------
__global__ __launch_bounds__(256, 3)
void attn_main(const short* __restrict__ QF, const short* __restrict__ KF,
               const short* __restrict__ VF, const short* __restrict__ WF,
               const float* __restrict__ batt, float* __restrict__ out) {
    int bid = blockIdx.x;
    int b   = bid / BLKS_PER_B;
    int g   = (bid % BLKS_PER_B) * TSTEP;
    int gend = g + TSTEP;

    int w   = threadIdx.x >> 6;
    int l   = threadIdx.x & 63;
    int r16 = l & 15;
    int lb  = l >> 4;

    const f32x4 z = {0.f, 0.f, 0.f, 0.f};

    while (g < gend) {
        int it   = tri_inv(g);
        int base = it * (it + 1) / 2;
        int jt0  = g - base;
        int cnt  = min(gend - g, it + 1 - jt0);
        int jt1  = jt0 + cnt;

        // Q frags (B-operand of swapped QK^T): lane holds Q[i=it*64+w*16+(l&15)][k]
        bf16x8 qf[2][2];
        {
            int rgq = it * 4 + w;
            #pragma unroll
            for (int c = 0; c < 2; ++c)
                #pragma unroll
                for (int ch = 0; ch < 2; ++ch)
                    qf[c][ch] = *(const bf16x8*)(QF + (((b * 256 + rgq) * 2 + c) * 2 + ch) * 512 + l * 8);
        }

        // O^T accumulators: o[ft][ch] holds O[i=r16][f = ft*16 + 4*lb + reg]
        f32x4 o[4][2];
        #pragma unroll
        for (int ft = 0; ft < 4; ++ft) { o[ft][0] = z; o[ft][1] = z; }

        bool hasdiag = (jt1 == it + 1);
        int nd_end   = hasdiag ? it : jt1;
        for (int jt = jt0; jt < nd_end; ++jt)
            do_tile<false>(b, it, jt, w, l, r16, lb, qf, o, KF, VF);
        if (hasdiag)
            do_tile<true>(b, it, it, w, l, r16, lb, qf, o, KF, VF);

        // ---- epilogue: acc = mfma(A=O-frag, B=W_attT-frag) -> i on regs, g on lanes ----
        bf16x8 ob[2][2];   // [c-chunk][ch]; element e=(s*4+reg) <- o[cc*2+s][ch][reg]
        #pragma unroll
        for (int cc = 0; cc < 2; ++cc)
            #pragma unroll
            for (int ch = 0; ch < 2; ++ch)
                #pragma unroll
                for (int s = 0; s < 2; ++s)
                    #pragma unroll
                    for (int reg = 0; reg < 4; ++reg)
                        ob[cc][ch][s * 4 + reg] = f2bf_s(o[cc * 2 + s][ch][reg]);

        bool whole = (jt0 == 0) && (jt1 == it + 1);
        int i0 = it * 64 + w * 16;             // wave's first q-row

        #pragma unroll
        for (int gt = 0; gt < 4; ++gt) {
            bf16x8 wa0 = *(const bf16x8*)(WF + ((gt * 2 + 0) * 64 + l) * 8);
            bf16x8 wa1 = *(const bf16x8*)(WF + ((gt * 2 + 1) * 64 + l) * 8);

            // D[m = i-within-16 on regs][n = g on lane&15]
            f32x4 a0 = __builtin_amdgcn_mfma_f32_16x16x32_bf16(ob[0][0], wa0, z, 0, 0, 0);
            a0 = __builtin_amdgcn_mfma_f32_16x16x32_bf16(ob[1][0], wa1, a0, 0, 0, 0);
            f32x4 a1 = __builtin_amdgcn_mfma_f32_16x16x32_bf16(ob[0][1], wa0, z, 0, 0, 0);
            a1 = __builtin_amdgcn_mfma_f32_16x16x32_bf16(ob[1][1], wa1, a1, 0, 0, 0);

            int gcol = gt * 16 + r16;
            if (whole) {
                float bb = batt[gcol];
                #pragma unroll
                for (int reg = 0; reg < 4; ++reg) {
                    int irow = i0 + lb * 4 + reg;
                    float2 st = {a0[reg] + bb, a1[reg] + bb};
                    *(float2*)(out + ((b * NN + irow) * 64 + gcol) * 2) = st;
                }
            } else {
                #pragma unroll
                for (int reg = 0; reg < 4; ++reg) {
                    int irow = i0 + lb * 4 + reg;
                    int idx = ((b * NN + irow) * 64 + gcol) * 2;
                    atomicAdd(out + idx,     a0[reg]);   // bias supplied by prefill
                    atomicAdd(out + idx + 1, a1[reg]);
                }
            }
        }

        g += cnt;
    }
}

// ---------------------------------------------------------------------------
extern "C" void kernel_launch(void* const* d_in, const int* in_sizes, int n_in,
                              void* d_out, int out_size, void* d_ws, size_t ws_size,
                              hipStream_t stream) {
    const float* Q  = (const float*)d_in[0];
    const float* K  = (const float*)d_in[1];
    const float* V  = (const float*)d_in[2];
    const float* W  = (const float*)d_in[3];
    const float* bA = (const float*)d_in[4];
    float* out = (float*)d_out;

    short* QF = (short*)d_ws;
    short* KF = QF + 2097152;
    short* VF = KF + 2097152;
    short* WF = VF + 2097152;

    prep_all<<<3586, 256, 0, stream>>>(Q, K, V, W, bA, QF, KF, VF, WF, out);
    attn_main<<<NB * BLKS_PER_B, 256, 0, stream>>>(QF, KF, VF, WF, bA, out);
}